// Round 2
// baseline (847.164 us; speedup 1.0000x reference)
//
#include <hip/hip_runtime.h>
#include <hip/hip_bf16.h>

#define H 160
#define W 160
#define HW (H*W)

__device__ inline float toF(float v) { return v; }
__device__ inline float toF(__hip_bfloat16 v) { return __bfloat162float(v); }
template <typename T> __device__ inline T fromF(float v);
template <> __device__ inline float fromF<float>(float v) { return v; }
template <> __device__ inline __hip_bfloat16 fromF<__hip_bfloat16>(float v) { return __float2bfloat16(v); }

// ---------------------------------------------------------------------------
// Conv3x3 (SAME) + BN + ReLU, single image, 128->128 channels, fp32 compute.
// Block: 256 threads. Tile: 16 wide x 8 high pixels x 32 output channels.
// Grid: (10, 20, 4).
// ---------------------------------------------------------------------------
template <typename Tin, typename Tout>
__global__ __launch_bounds__(256) void conv_bn_relu_kernel(
    const Tin* __restrict__ in,        // (128,160,160)
    const float* __restrict__ w,       // (128,128,3,3) this layer
    const float* __restrict__ gamma,   // (128)
    const float* __restrict__ beta,
    const float* __restrict__ mean,
    const float* __restrict__ var,
    Tout* __restrict__ out)            // (128,160,160)
{
    __shared__ float s_in[16][10 * 18];   // 11.25 KB
    __shared__ float s_w[144][32];        // 18.0 KB

    const int tid = threadIdx.x;
    const int bx = blockIdx.x;   // 0..9   x-tile (16 wide)
    const int by = blockIdx.y;   // 0..19  y-tile (8 high)
    const int bco = blockIdx.z;  // 0..3   32-channel group

    const int cg  = tid >> 6;          // 0..3 -> co base cg*8
    const int pid = tid & 63;
    const int px  = pid & 15;          // 0..15
    const int py  = pid >> 4;          // 0..3 ; second pixel at py+4

    const int tx0 = bx * 16 - 1;
    const int ty0 = by * 8 - 1;

    float acc0[8], acc1[8];
#pragma unroll
    for (int i = 0; i < 8; ++i) { acc0[i] = 0.f; acc1[i] = 0.f; }

    for (int ci0 = 0; ci0 < 128; ci0 += 16) {
        // ---- stage input tile: 16 ci x 10 rows x 18 cols
        for (int i = tid; i < 16 * 180; i += 256) {
            int ci  = i / 180;
            int rem = i - ci * 180;
            int iy  = rem / 18;
            int ix  = rem - iy * 18;
            int gy = ty0 + iy, gx = tx0 + ix;
            float v = 0.f;
            if ((unsigned)gy < (unsigned)H && (unsigned)gx < (unsigned)W)
                v = toF(in[(ci0 + ci) * HW + gy * W + gx]);
            s_in[ci][rem] = v;
        }
        // ---- stage weights: rk = ci*9 + k (0..143), co (0..31)
        for (int i = tid; i < 144 * 32; i += 256) {
            int co = i & 31;
            int rk = i >> 5;               // ci*9 + k
            s_w[rk][co] = w[(bco * 32 + co) * 1152 + ci0 * 9 + rk];
        }
        __syncthreads();

#pragma unroll 2
        for (int ci = 0; ci < 16; ++ci) {
            const float* srow = &s_in[ci][0];
#pragma unroll
            for (int r = 0; r < 3; ++r) {
#pragma unroll
                for (int s = 0; s < 3; ++s) {
                    float x0 = srow[(py + r) * 18 + px + s];
                    float x1 = srow[(py + 4 + r) * 18 + px + s];
                    const float4* w4 = (const float4*)&s_w[ci * 9 + r * 3 + s][cg * 8];
                    float4 wa = w4[0];
                    float4 wb = w4[1];
                    acc0[0] += x0 * wa.x; acc1[0] += x1 * wa.x;
                    acc0[1] += x0 * wa.y; acc1[1] += x1 * wa.y;
                    acc0[2] += x0 * wa.z; acc1[2] += x1 * wa.z;
                    acc0[3] += x0 * wa.w; acc1[3] += x1 * wa.w;
                    acc0[4] += x0 * wb.x; acc1[4] += x1 * wb.x;
                    acc0[5] += x0 * wb.y; acc1[5] += x1 * wb.y;
                    acc0[6] += x0 * wb.z; acc1[6] += x1 * wb.z;
                    acc0[7] += x0 * wb.w; acc1[7] += x1 * wb.w;
                }
            }
        }
        __syncthreads();
    }

    // ---- epilogue: BN + ReLU, write two pixels per co
    const int ox  = bx * 16 + px;
    const int oy0 = by * 8 + py;
    const int oy1 = oy0 + 4;
#pragma unroll
    for (int co = 0; co < 8; ++co) {
        int c = bco * 32 + cg * 8 + co;
        float inv   = gamma[c] * rsqrtf(var[c] + 1e-5f);
        float shift = beta[c] - mean[c] * inv;
        float v0 = acc0[co] * inv + shift;
        float v1 = acc1[co] * inv + shift;
        out[c * HW + oy0 * W + ox] = fromF<Tout>(fmaxf(v0, 0.f));
        out[c * HW + oy1 * W + ox] = fromF<Tout>(fmaxf(v1, 0.f));
    }
}

// ---------------------------------------------------------------------------
// Projection: mask_feats[o][p] = sum_c x[c][p]*proj_w[o][c] + proj_b[o]
// ---------------------------------------------------------------------------
template <typename Tin>
__global__ __launch_bounds__(256) void proj_kernel(
    const Tin* __restrict__ x,        // (128,160,160)
    const float* __restrict__ pw,     // (8,128)
    const float* __restrict__ pb,     // (8)
    float* __restrict__ mf)           // (8,160,160)
{
    __shared__ float spw[8 * 128];
    const int tid = threadIdx.x;
    for (int i = tid; i < 8 * 128; i += 256) spw[i] = pw[i];
    __syncthreads();

    const int p = blockIdx.x * 256 + tid;   // < 25600
    float acc[8];
#pragma unroll
    for (int o = 0; o < 8; ++o) acc[o] = 0.f;
    for (int c = 0; c < 128; ++c) {
        float v = toF(x[c * HW + p]);
#pragma unroll
        for (int o = 0; o < 8; ++o) acc[o] += v * spw[o * 128 + c];
    }
#pragma unroll
    for (int o = 0; o < 8; ++o) mf[o * HW + p] = acc[o] + pb[o];
}

// ---------------------------------------------------------------------------
// Controller params at detection points (fp32 throughout).
// ---------------------------------------------------------------------------
__global__ __launch_bounds__(256) void ctrl_kernel(
    const float* __restrict__ feat,   // (128,160,160) batch 0
    const float* __restrict__ cw,     // (169,128,3,3)
    const float* __restrict__ cb,     // (169)
    const int*   __restrict__ det,    // (100,2) [x,y]
    float* __restrict__ params)       // (100,169)
{
    __shared__ float patch[1152];
    const int tid = threadIdx.x;
    const int k = blockIdx.x;
    const int xk = det[2 * k];
    const int yk = det[2 * k + 1];

    for (int i = tid; i < 1152; i += 256) {
        int ci  = i / 9;
        int rem = i - ci * 9;
        int r = rem / 3, s = rem - r * 3;
        int gy = yk + r - 1, gx = xk + s - 1;
        float v = 0.f;
        if ((unsigned)gy < (unsigned)H && (unsigned)gx < (unsigned)W)
            v = feat[ci * HW + gy * W + gx];
        patch[i] = v;
    }
    __syncthreads();

    if (tid < 169) {
        float acc = cb[tid];
        const float4* cw4 = (const float4*)&cw[tid * 1152];
        const float4* p4  = (const float4*)patch;
        for (int i = 0; i < 288; ++i) {
            float4 a = p4[i];
            float4 b = cw4[i];
            acc += a.x * b.x + a.y * b.y + a.z * b.z + a.w * b.w;
        }
        params[k * 169 + tid] = acc;
    }
}

// ---------------------------------------------------------------------------
// Head MLP: per (k, pixel): h=[relx,rely,f0..f7]; 3 layers from params[k].
// ---------------------------------------------------------------------------
__global__ __launch_bounds__(256) void head_kernel(
    const float* __restrict__ mf,      // (8,160,160)
    const float* __restrict__ params,  // (100,169)
    const int*   __restrict__ det,     // (100,2)
    float* __restrict__ out)           // (100,160,160)
{
    __shared__ float sp[169];
    const int tid = threadIdx.x;
    const int k = blockIdx.y;
    if (tid < 169) sp[tid] = params[k * 169 + tid];
    __syncthreads();

    const int p = blockIdx.x * 256 + tid;   // < 25600
    const int x = p % W;
    const int y = p / W;
    const float rel0 = (float)(det[2 * k] * 4) - (float)(x * 4 + 2);
    const float rel1 = (float)(det[2 * k + 1] * 4) - (float)(y * 4 + 2);

    float f[8];
#pragma unroll
    for (int o = 0; o < 8; ++o) f[o] = mf[o * HW + p];

    float h0[8];
#pragma unroll
    for (int o = 0; o < 8; ++o) {
        float a = sp[152 + o] + sp[o * 10] * rel0 + sp[o * 10 + 1] * rel1;
#pragma unroll
        for (int c = 0; c < 8; ++c) a += sp[o * 10 + 2 + c] * f[c];
        h0[o] = fmaxf(a, 0.f);
    }
    float h1[8];
#pragma unroll
    for (int o = 0; o < 8; ++o) {
        float a = sp[160 + o];
#pragma unroll
        for (int c = 0; c < 8; ++c) a += sp[80 + o * 8 + c] * h0[c];
        h1[o] = fmaxf(a, 0.f);
    }
    float r = sp[168];
#pragma unroll
    for (int c = 0; c < 8; ++c) r += sp[144 + c] * h1[c];

    out[k * HW + p] = r;
}

// ---------------------------------------------------------------------------
extern "C" void kernel_launch(void* const* d_in, const int* in_sizes, int n_in,
                              void* d_out, int out_size, void* d_ws, size_t ws_size,
                              hipStream_t stream)
{
    const float* cnn    = (const float*)d_in[0];   // (4,128,160,160); batch 0 used
    const float* towerw = (const float*)d_in[1];   // (4,128,128,3,3)
    const float* gamma  = (const float*)d_in[2];   // (4,128)
    const float* beta   = (const float*)d_in[3];
    const float* meanp  = (const float*)d_in[4];
    const float* varp   = (const float*)d_in[5];
    const float* projw  = (const float*)d_in[6];   // (8,128)
    const float* projb  = (const float*)d_in[7];   // (8)
    const float* ctrlw  = (const float*)d_in[8];   // (169,128,3,3)
    const float* ctrlb  = (const float*)d_in[9];   // (169)
    const int*   det    = (const int*)d_in[10];    // (100,2)
    float* out = (float*)d_out;

    const dim3 cgrid(10, 20, 4);
    const dim3 cblk(256);

    // fp32 path needs 27,101,200 B of ws; bf16 path needs 7,440,400 B.
    const size_t FP32_NEED = 27101200ull;

    if (ws_size >= FP32_NEED) {
        // ---------------- Path A: all-fp32 (27.1 MB ws) ----------------
        float* ws = (float*)d_ws;
        float* buf0   = ws;                // 3,276,800 floats
        float* buf1   = ws + 3276800;      // 3,276,800 floats
        float* mf     = ws + 6553600;      // 204,800 floats
        float* params = ws + 6758400;      // 16,900 floats

        conv_bn_relu_kernel<float, float><<<cgrid, cblk, 0, stream>>>(
            cnn, towerw + 0 * 147456, gamma + 0, beta + 0, meanp + 0, varp + 0, buf0);
        conv_bn_relu_kernel<float, float><<<cgrid, cblk, 0, stream>>>(
            buf0, towerw + 1 * 147456, gamma + 128, beta + 128, meanp + 128, varp + 128, buf1);
        conv_bn_relu_kernel<float, float><<<cgrid, cblk, 0, stream>>>(
            buf1, towerw + 2 * 147456, gamma + 256, beta + 256, meanp + 256, varp + 256, buf0);
        conv_bn_relu_kernel<float, float><<<cgrid, cblk, 0, stream>>>(
            buf0, towerw + 3 * 147456, gamma + 384, beta + 384, meanp + 384, varp + 384, buf1);

        proj_kernel<float><<<dim3(100), cblk, 0, stream>>>(buf1, projw, projb, mf);
        ctrl_kernel<<<dim3(100), cblk, 0, stream>>>(cnn, ctrlw, ctrlb, det, params);
        head_kernel<<<dim3(100, 100), cblk, 0, stream>>>(mf, params, det, out);
    } else {
        // ---------------- Path B: bf16 activations (7.44 MB ws) ----------------
        // A lives in d_out (6.55 MB <= 10.24 MB; dead before head_kernel writes).
        __hip_bfloat16* A  = (__hip_bfloat16*)d_out;
        __hip_bfloat16* Bb = (__hip_bfloat16*)d_ws;                    // 6,553,600 B
        float* mf     = (float*)((char*)d_ws + 6553600);               // 819,200 B
        float* params = mf + 204800;                                   // 67,600 B

        conv_bn_relu_kernel<float, __hip_bfloat16><<<cgrid, cblk, 0, stream>>>(
            cnn, towerw + 0 * 147456, gamma + 0, beta + 0, meanp + 0, varp + 0, A);
        conv_bn_relu_kernel<__hip_bfloat16, __hip_bfloat16><<<cgrid, cblk, 0, stream>>>(
            A, towerw + 1 * 147456, gamma + 128, beta + 128, meanp + 128, varp + 128, Bb);
        conv_bn_relu_kernel<__hip_bfloat16, __hip_bfloat16><<<cgrid, cblk, 0, stream>>>(
            Bb, towerw + 2 * 147456, gamma + 256, beta + 256, meanp + 256, varp + 256, A);
        conv_bn_relu_kernel<__hip_bfloat16, __hip_bfloat16><<<cgrid, cblk, 0, stream>>>(
            A, towerw + 3 * 147456, gamma + 384, beta + 384, meanp + 384, varp + 384, Bb);

        proj_kernel<__hip_bfloat16><<<dim3(100), cblk, 0, stream>>>(Bb, projw, projb, mf);
        ctrl_kernel<<<dim3(100), cblk, 0, stream>>>(cnn, ctrlw, ctrlb, det, params);
        head_kernel<<<dim3(100, 100), cblk, 0, stream>>>(mf, params, det, out);
    }
}

// Round 4
// 129.748 us; speedup vs baseline: 6.5293x; 6.5293x over previous
//
#include <hip/hip_runtime.h>
#include <hip/hip_bf16.h>

#define H 160
#define W 160
#define HW 25600
#define ROWB 40960      // W * 256 bytes per NHWC row
#define PIXB 256        // bytes per pixel (128 ch x 2B)

typedef __attribute__((ext_vector_type(8))) short bf16x8;
typedef __attribute__((ext_vector_type(4))) float f32x4;
typedef __attribute__((ext_vector_type(8))) unsigned short ushort8v;
typedef __attribute__((ext_vector_type(4))) unsigned short ushort4v;

typedef __attribute__((address_space(1))) const unsigned int gu32;
typedef __attribute__((address_space(3))) unsigned int lu32;

__device__ __forceinline__ void gload16(const void* g, void* l) {
    __builtin_amdgcn_global_load_lds((gu32*)g, (lu32*)l, 16, 0, 0);
}

__device__ __forceinline__ unsigned short f2b(float f) {
    unsigned int u = __float_as_uint(f);
    unsigned int r = (u + 0x7fffu + ((u >> 16) & 1u)) >> 16;
    return (unsigned short)r;
}
__device__ __forceinline__ float b2f(unsigned short b) {
    return __uint_as_float(((unsigned int)b) << 16);
}

// ---------------------------------------------------------------------------
// d_out byte layout (10,240,000 B total; all dead before head_kernel writes):
//   [0, 6553600)        act X  (swizzled NHWC bf16)
//   [6553600, 7733248)  wbf: 4 layers x 9 taps x 32768 B (pre-swizzled [co][ci])
//   [7733248, 7737344)  invshift: 4 layers x (inv[128], shift[128]) f32
// ws byte layout (7,440,400 B -- exactly the round-2-proven budget):
//   [0, 6553600)        act Y
//   [6553600, 7372800)  mf (8 x 25600 f32)
//   [7372800, 7440400)  params (100 x 169 f32)
// ---------------------------------------------------------------------------

// ===========================================================================
// prep_weights: tower_w fp32 (4,128,128,3,3) -> bf16 planes [l][tap][co][ci]
// pre-swizzled: byte = co*256 + ((ci*2) ^ ((co&7)<<5)).  Also BN inv/shift.
// ===========================================================================
__global__ __launch_bounds__(256) void prep_weights(
    const float* __restrict__ tw,
    const float* __restrict__ gamma, const float* __restrict__ beta,
    const float* __restrict__ mean,  const float* __restrict__ var,
    char* __restrict__ wbf, float* __restrict__ invshift)
{
    int idx = blockIdx.x * 256 + threadIdx.x;     // 589,824 total (exact grid)
    int ci = idx & 127;
    int co = (idx >> 7) & 127;
    int lt = idx >> 14;           // l*9 + tap
    int l  = lt / 9;
    int tap = lt - l * 9;
    float v = tw[(((l * 128 + co) * 128 + ci) * 9) + tap];
    int plane = (l * 9 + tap) * 32768;
    int byte = co * 256 + ((ci * 2) ^ ((co & 7) << 5));
    *(unsigned short*)(wbf + plane + byte) = f2b(v);

    if (blockIdx.x == 0) {
        for (int c = threadIdx.x; c < 512; c += 256) {
            int ll = c >> 7, ch = c & 127;
            float inv = gamma[ll * 128 + ch] * rsqrtf(var[ll * 128 + ch] + 1e-5f);
            float sh  = beta[ll * 128 + ch] - mean[ll * 128 + ch] * inv;
            invshift[ll * 256 + ch] = inv;
            invshift[ll * 256 + 128 + ch] = sh;
        }
    }
}

// ===========================================================================
// prep_input: cnn batch0 fp32 NCHW -> swizzled NHWC bf16 (act X)
// thread = (pixel, 16B-chunk): reads 8 strided fp32, writes 16B swizzled.
// ===========================================================================
__global__ __launch_bounds__(256) void prep_input(
    const float* __restrict__ cnn, char* __restrict__ actX)
{
    int idx = blockIdx.x * 256 + threadIdx.x;   // 409,600 total (exact grid)
    int cb = idx & 15;
    int p  = idx >> 4;
    int x  = p % W;
    int key = (x & 7) << 5;
    int ci0 = cb * 8;
    ushort8v o;
#pragma unroll
    for (int j = 0; j < 8; ++j)
        o[j] = f2b(cnn[(ci0 + j) * HW + p]);
    *(ushort8v*)(actX + p * 256 + ((cb * 16) ^ key)) = o;
}

// ===========================================================================
// conv_mfma: 3x3 SAME conv 128->128 + BN + ReLU on swizzled NHWC bf16.
// Block: 256 thr (4 waves), tile 128co x 64px (16w x 4h). Grid (10,40).
// Per tap: stage W[co][ci] 32KB (linear global_load_lds), 4 K-steps x 8 MFMA.
// Staging is DMA-safe: all loads use clamped in-bounds addresses (no divergent
// global_load_lds); OOB chunks are zeroed via ds_write after a barrier.
// ===========================================================================
__global__ __launch_bounds__(256, 2) void conv_mfma(
    const char* __restrict__ actin,
    const char* __restrict__ wbf_l,      // 9 x 32768 B
    const float* __restrict__ invshift_l,// 256 f32
    char* __restrict__ actout)
{
    __shared__ __align__(16) char smem[61440];
    char* IT = smem;                 // 27648 B : [6 rows][18 px][256 B]
    char* WT = smem + 27648;         // 32768 B : [128 co][256 B]
    float* sInv = (float*)(smem + 60416); // 256 f32

    const int tid  = threadIdx.x;
    const int lane = tid & 63;
    const int wave = tid >> 6;
    const int g    = lane >> 4;
    const int i15  = lane & 15;
    const int wc   = wave >> 1;      // co half (64 co)
    const int wp   = wave & 1;       // px half (2 rows)

    const int bx = blockIdx.x;       // 0..9
    const int by = blockIdx.y;       // 0..39
    const int tx0 = bx * 16 - 1;
    const int ty0 = by * 4 - 1;

    // ---- stage input tile: 1728 x 16B chunks, clamped addresses (in-bounds)
    for (int it = 0; it < 7; ++it) {
        int c = it * 256 + tid;
        if (c < 1728) {                        // whole waves only (1728 % 64 == 0)
            int row  = c / 288;
            int rem  = c - row * 288;
            int px_i = rem >> 4;
            int bo   = (rem & 15) * 16;
            int gy = ty0 + row, gx = tx0 + px_i;
            int cy = min(max(gy, 0), H - 1);
            int cx = min(max(gx, 0), W - 1);
            char* ldsb = IT + (it * 256 + (tid & ~63)) * 16; // wave-uniform base
            gload16(actin + cy * ROWB + cx * 256 + bo, ldsb);
        }
    }
    // ---- stage weights for tap 0 (2048 chunks, no divergence)
    for (int it = 0; it < 8; ++it) {
        int c = it * 256 + tid;
        char* ldsb = WT + (it * 256 + (tid & ~63)) * 16;
        gload16(wbf_l + c * 16, ldsb);
    }
    __syncthreads();   // drains all DMA

    // ---- zero the OOB border chunks + load BN constants
    for (int c = tid; c < 1728; c += 256) {
        int row  = c / 288;
        int rem  = c - row * 288;
        int px_i = rem >> 4;
        int gy = ty0 + row, gx = tx0 + px_i;
        if ((unsigned)gy >= (unsigned)H || (unsigned)gx >= (unsigned)W) {
            f32x4 z = {0.f, 0.f, 0.f, 0.f};
            *(f32x4*)(IT + c * 16) = z;
        }
    }
    sInv[tid] = invshift_l[tid];
    __syncthreads();

    f32x4 acc[4][2];
#pragma unroll
    for (int cf = 0; cf < 4; ++cf)
#pragma unroll
        for (int pf = 0; pf < 2; ++pf)
            acc[cf][pf] = (f32x4){0.f, 0.f, 0.f, 0.f};

    const int keyw = (i15 & 7) << 5;  // weight-read swizzle key

    for (int tap = 0; tap < 9; ++tap) {
        int r = tap / 3;
        int s = tap - r * 3;
        int keyb = (((i15 + s + 7) & 7)) << 5;  // (tx0 + i15 + s) & 7
        int bpix0 = (wp * 2 + 0 + r) * 4608 + (i15 + s) * 256;
        int bpix1 = (wp * 2 + 1 + r) * 4608 + (i15 + s) * 256;

#pragma unroll
        for (int kk = 0; kk < 4; ++kk) {
            int kb = kk * 64 + g * 16;
            bf16x8 a0 = *(const bf16x8*)(WT + (wc * 64 + 0 * 16 + i15) * 256 + (kb ^ keyw));
            bf16x8 a1 = *(const bf16x8*)(WT + (wc * 64 + 1 * 16 + i15) * 256 + (kb ^ keyw));
            bf16x8 a2 = *(const bf16x8*)(WT + (wc * 64 + 2 * 16 + i15) * 256 + (kb ^ keyw));
            bf16x8 a3 = *(const bf16x8*)(WT + (wc * 64 + 3 * 16 + i15) * 256 + (kb ^ keyw));
            bf16x8 b0 = *(const bf16x8*)(IT + bpix0 + (kb ^ keyb));
            bf16x8 b1 = *(const bf16x8*)(IT + bpix1 + (kb ^ keyb));
            acc[0][0] = __builtin_amdgcn_mfma_f32_16x16x32_bf16(a0, b0, acc[0][0], 0, 0, 0);
            acc[0][1] = __builtin_amdgcn_mfma_f32_16x16x32_bf16(a0, b1, acc[0][1], 0, 0, 0);
            acc[1][0] = __builtin_amdgcn_mfma_f32_16x16x32_bf16(a1, b0, acc[1][0], 0, 0, 0);
            acc[1][1] = __builtin_amdgcn_mfma_f32_16x16x32_bf16(a1, b1, acc[1][1], 0, 0, 0);
            acc[2][0] = __builtin_amdgcn_mfma_f32_16x16x32_bf16(a2, b0, acc[2][0], 0, 0, 0);
            acc[2][1] = __builtin_amdgcn_mfma_f32_16x16x32_bf16(a2, b1, acc[2][1], 0, 0, 0);
            acc[3][0] = __builtin_amdgcn_mfma_f32_16x16x32_bf16(a3, b0, acc[3][0], 0, 0, 0);
            acc[3][1] = __builtin_amdgcn_mfma_f32_16x16x32_bf16(a3, b1, acc[3][1], 0, 0, 0);
        }
        __syncthreads();
        if (tap < 8) {
            const char* wtap = wbf_l + (tap + 1) * 32768;
            for (int it = 0; it < 8; ++it) {
                int c = it * 256 + tid;
                char* ldsb = WT + (it * 256 + (tid & ~63)) * 16;
                gload16(wtap + c * 16, ldsb);
            }
            __syncthreads();
        }
    }

    // ---- epilogue: BN + ReLU + bf16 + swizzled NHWC store
    const int gx = bx * 16 + i15;
    const int keyo = (gx & 7) << 5;   // == keyw
#pragma unroll
    for (int cf = 0; cf < 4; ++cf) {
        int co0 = wc * 64 + cf * 16 + g * 4;
        f32x4 inv4 = *(const f32x4*)&sInv[co0];
        f32x4 sh4  = *(const f32x4*)&sInv[128 + co0];
#pragma unroll
        for (int pf = 0; pf < 2; ++pf) {
            int gy = by * 4 + wp * 2 + pf;
            f32x4 v = acc[cf][pf];
            ushort4v o;
            o.x = f2b(fmaxf(v.x * inv4.x + sh4.x, 0.f));
            o.y = f2b(fmaxf(v.y * inv4.y + sh4.y, 0.f));
            o.z = f2b(fmaxf(v.z * inv4.z + sh4.z, 0.f));
            o.w = f2b(fmaxf(v.w * inv4.w + sh4.w, 0.f));
            *(ushort4v*)(actout + gy * ROWB + gx * 256 + ((co0 * 2) ^ keyo)) = o;
        }
    }
}

// ===========================================================================
// proj: swizzled NHWC bf16 -> mask feats (8,HW) f32
// ===========================================================================
__global__ __launch_bounds__(256) void proj_kernel(
    const char* __restrict__ X, const float* __restrict__ pw,
    const float* __restrict__ pb, float* __restrict__ mf)
{
    __shared__ float spw[1024];
    const int tid = threadIdx.x;
    for (int i = tid; i < 1024; i += 256) spw[i] = pw[i];
    __syncthreads();

    const int p = blockIdx.x * 256 + tid;
    const int x = p % W;
    const int key = (x & 7) << 5;
    float acc[8];
#pragma unroll
    for (int o = 0; o < 8; ++o) acc[o] = 0.f;
    for (int cb = 0; cb < 16; ++cb) {
        ushort8v v = *(const ushort8v*)(X + p * 256 + ((cb * 16) ^ key));
#pragma unroll
        for (int j = 0; j < 8; ++j) {
            float f = b2f(v[j]);
            int ci = cb * 8 + j;
#pragma unroll
            for (int o = 0; o < 8; ++o) acc[o] += f * spw[o * 128 + ci];
        }
    }
#pragma unroll
    for (int o = 0; o < 8; ++o) mf[o * HW + p] = acc[o] + pb[o];
}

// ===========================================================================
// ctrl: controller conv evaluated only at the K=100 detection points (fp32)
// ===========================================================================
__global__ __launch_bounds__(256) void ctrl_kernel(
    const float* __restrict__ feat, const float* __restrict__ cw,
    const float* __restrict__ cb, const int* __restrict__ det,
    float* __restrict__ params)
{
    __shared__ float patch[1152];
    const int tid = threadIdx.x;
    const int k = blockIdx.x;
    const int xk = det[2 * k];
    const int yk = det[2 * k + 1];

    for (int i = tid; i < 1152; i += 256) {
        int ci = i / 9;
        int rem = i - ci * 9;
        int r = rem / 3, s = rem - r * 3;
        int gy = yk + r - 1, gx = xk + s - 1;
        float v = 0.f;
        if ((unsigned)gy < (unsigned)H && (unsigned)gx < (unsigned)W)
            v = feat[ci * HW + gy * W + gx];
        patch[i] = v;
    }
    __syncthreads();

    if (tid < 169) {
        float acc = cb[tid];
        const float4* cw4 = (const float4*)&cw[tid * 1152];
        const float4* p4  = (const float4*)patch;
        for (int i = 0; i < 288; ++i) {
            float4 a = p4[i];
            float4 b = cw4[i];
            acc += a.x * b.x + a.y * b.y + a.z * b.z + a.w * b.w;
        }
        params[k * 169 + tid] = acc;
    }
}

// ===========================================================================
// head: per (k, pixel) 3-layer MLP
// ===========================================================================
__global__ __launch_bounds__(256) void head_kernel(
    const float* __restrict__ mf, const float* __restrict__ params,
    const int* __restrict__ det, float* __restrict__ out)
{
    __shared__ float sp[169];
    const int tid = threadIdx.x;
    const int k = blockIdx.y;
    if (tid < 169) sp[tid] = params[k * 169 + tid];
    __syncthreads();

    const int p = blockIdx.x * 256 + tid;
    const int x = p % W;
    const int y = p / W;
    const float rel0 = (float)(det[2 * k] * 4) - (float)(x * 4 + 2);
    const float rel1 = (float)(det[2 * k + 1] * 4) - (float)(y * 4 + 2);

    float f[8];
#pragma unroll
    for (int o = 0; o < 8; ++o) f[o] = mf[o * HW + p];

    float h0[8];
#pragma unroll
    for (int o = 0; o < 8; ++o) {
        float a = sp[152 + o] + sp[o * 10] * rel0 + sp[o * 10 + 1] * rel1;
#pragma unroll
        for (int c = 0; c < 8; ++c) a += sp[o * 10 + 2 + c] * f[c];
        h0[o] = fmaxf(a, 0.f);
    }
    float h1[8];
#pragma unroll
    for (int o = 0; o < 8; ++o) {
        float a = sp[160 + o];
#pragma unroll
        for (int c = 0; c < 8; ++c) a += sp[80 + o * 8 + c] * h0[c];
        h1[o] = fmaxf(a, 0.f);
    }
    float r = sp[168];
#pragma unroll
    for (int c = 0; c < 8; ++c) r += sp[144 + c] * h1[c];

    out[k * HW + p] = r;
}

// ===========================================================================
extern "C" void kernel_launch(void* const* d_in, const int* in_sizes, int n_in,
                              void* d_out, int out_size, void* d_ws, size_t ws_size,
                              hipStream_t stream)
{
    const float* cnn    = (const float*)d_in[0];
    const float* towerw = (const float*)d_in[1];
    const float* gamma  = (const float*)d_in[2];
    const float* beta   = (const float*)d_in[3];
    const float* meanp  = (const float*)d_in[4];
    const float* varp   = (const float*)d_in[5];
    const float* projw  = (const float*)d_in[6];
    const float* projb  = (const float*)d_in[7];
    const float* ctrlw  = (const float*)d_in[8];
    const float* ctrlb  = (const float*)d_in[9];
    const int*   det    = (const int*)d_in[10];
    float* out = (float*)d_out;

    char*  outb     = (char*)d_out;
    char*  X        = outb;                          // 6,553,600 B
    char*  wbf      = outb + 6553600;                // 1,179,648 B
    float* invshift = (float*)(outb + 7733248);      // 4,096 B

    char*  Y      = (char*)d_ws;                     // 6,553,600 B
    float* mf     = (float*)((char*)d_ws + 6553600); // 819,200 B
    float* params = (float*)((char*)d_ws + 7372800); // 67,600 B

    const dim3 blk(256);

    prep_weights<<<dim3(2304), blk, 0, stream>>>(towerw, gamma, beta, meanp, varp,
                                                 wbf, invshift);
    prep_input<<<dim3(1600), blk, 0, stream>>>(cnn, X);

    const dim3 cgrid(10, 40);
    conv_mfma<<<cgrid, blk, 0, stream>>>(X, wbf + 0 * 294912, invshift + 0 * 256, Y);
    conv_mfma<<<cgrid, blk, 0, stream>>>(Y, wbf + 1 * 294912, invshift + 1 * 256, X);
    conv_mfma<<<cgrid, blk, 0, stream>>>(X, wbf + 2 * 294912, invshift + 2 * 256, Y);
    conv_mfma<<<cgrid, blk, 0, stream>>>(Y, wbf + 3 * 294912, invshift + 3 * 256, X);

    proj_kernel<<<dim3(100), blk, 0, stream>>>(X, projw, projb, mf);
    ctrl_kernel<<<dim3(100), blk, 0, stream>>>(cnn, ctrlw, ctrlb, det, params);
    head_kernel<<<dim3(100, 100), blk, 0, stream>>>(mf, params, det, out);
}

// Round 6
// 123.674 us; speedup vs baseline: 6.8500x; 1.0491x over previous
//
#include <hip/hip_runtime.h>
#include <hip/hip_bf16.h>

#define H 160
#define W 160
#define HW 25600
#define ROWB 40960      // W * 256 bytes per NHWC row

typedef __attribute__((ext_vector_type(8))) short bf16x8;
typedef __attribute__((ext_vector_type(4))) float f32x4;
typedef __attribute__((ext_vector_type(8))) unsigned short ushort8v;
typedef __attribute__((ext_vector_type(4))) unsigned short ushort4v;

typedef __attribute__((address_space(1))) const unsigned int gu32;
typedef __attribute__((address_space(3))) unsigned int lu32;

__device__ __forceinline__ void gload16(const void* g, void* l) {
    __builtin_amdgcn_global_load_lds((gu32*)g, (lu32*)l, 16, 0, 0);
}

__device__ __forceinline__ unsigned short f2b(float f) {
    unsigned int u = __float_as_uint(f);
    unsigned int r = (u + 0x7fffu + ((u >> 16) & 1u)) >> 16;
    return (unsigned short)r;
}
__device__ __forceinline__ float b2f(unsigned short b) {
    return __uint_as_float(((unsigned int)b) << 16);
}

#define LGKM0() asm volatile("s_waitcnt lgkmcnt(0)" ::: "memory")
#define BARRIER() asm volatile("s_barrier" ::: "memory")

// ---------------------------------------------------------------------------
// d_out scratch layout (10,240,000 B; dead until head_kernel rewrites it):
//   [0, 6553600)        act X  (swizzled NHWC bf16)
//   [6553600, 7733248)  wbf: 4 layers x 36 planes x 8192 B ([tap][kk][co][64B])
//   [7733248, 7737344)  invshift: 4 layers x (inv[128], shift[128]) f32
// ws layout (7,440,400 B — proven budget):
//   [0, 6553600)        act Y
//   [6553600, 7372800)  mf (8 x 25600 f32)
//   [7372800, 7440400)  params (100 x 169 f32)
// ---------------------------------------------------------------------------

// ===========================================================================
// prep_weights: fp32 (4,128,128,3,3) -> bf16 planes [l][tap][kk][co][32ci]
// (linear, no swizzle — 64-B co-stride is minimally bank-aliased on read)
// ===========================================================================
__global__ __launch_bounds__(256) void prep_weights(
    const float* __restrict__ tw,
    const float* __restrict__ gamma, const float* __restrict__ beta,
    const float* __restrict__ mean,  const float* __restrict__ var,
    char* __restrict__ wbf, float* __restrict__ invshift)
{
    int idx = blockIdx.x * 256 + threadIdx.x;     // 589,824 exact
    int ci = idx & 127;
    int co = (idx >> 7) & 127;
    int lt = idx >> 14;           // l*9 + tap
    int l  = lt / 9;
    int tap = lt - l * 9;
    int kk = ci >> 5;
    int cw = ci & 31;
    float v = tw[(((l * 128 + co) * 128 + ci) * 9) + tap];
    *(unsigned short*)(wbf + (lt * 4 + kk) * 8192 + co * 64 + cw * 2) = f2b(v);

    if (blockIdx.x == 0) {
        for (int c = threadIdx.x; c < 512; c += 256) {
            int ll = c >> 7, ch = c & 127;
            float inv = gamma[ll * 128 + ch] * rsqrtf(var[ll * 128 + ch] + 1e-5f);
            float sh  = beta[ll * 128 + ch] - mean[ll * 128 + ch] * inv;
            invshift[ll * 256 + ch] = inv;
            invshift[ll * 256 + 128 + ch] = sh;
        }
    }
}

// ===========================================================================
// prep_input: cnn batch0 fp32 NCHW -> swizzled NHWC bf16 (act X)
// ===========================================================================
__global__ __launch_bounds__(256) void prep_input(
    const float* __restrict__ cnn, char* __restrict__ actX)
{
    int idx = blockIdx.x * 256 + threadIdx.x;   // 409,600 exact
    int cb = idx & 15;
    int p  = idx >> 4;
    int x  = p % W;
    int key = (x & 7) << 5;
    int ci0 = cb * 8;
    ushort8v o;
#pragma unroll
    for (int j = 0; j < 8; ++j)
        o[j] = f2b(cnn[(ci0 + j) * HW + p]);
    *(ushort8v*)(actX + p * 256 + ((cb * 16) ^ key)) = o;
}

// ===========================================================================
// conv_mfma: 3x3 SAME conv 128->128 (+BN+ReLU), pipelined weight staging.
// Block 256 thr (4 waves), tile 128co x 64px (16w x 4h). Grid (10,40).
// 36 stages (9 taps x 4 kk): issue plane j+3 -> vmcnt(4) -> 8 MFMA -> barrier.
// PROJ=1: final layer keeps activations in LDS and emits the 8-ch projection.
// ===========================================================================
template <int PROJ>
__global__ __launch_bounds__(256, 2) void conv_mfma(
    const char* __restrict__ actin,
    const char* __restrict__ wpl,         // 36 x 8192 B
    const float* __restrict__ invshift_l, // 256 f32
    char* __restrict__ actout,            // PROJ=0
    const float* __restrict__ pw,         // PROJ=1: (8,128)
    const float* __restrict__ pb,         // (8)
    float* __restrict__ mf)               // (8,HW)
{
    __shared__ __align__(16) char smem[60416];
    char* IT = smem;                 // 27648 B : [6 rows][18 px][256 B]
    char* WQ = smem + 27648;         // 4 x 8192 B quarter-buffers

    const int tid  = threadIdx.x;
    const int lane = tid & 63;
    const int wave = tid >> 6;
    const int g    = lane >> 4;
    const int i15  = lane & 15;
    const int wc   = wave >> 1;
    const int wp   = wave & 1;

    const int bx = blockIdx.x;
    const int by = blockIdx.y;
    const int tx0 = bx * 16 - 1;
    const int ty0 = by * 4 - 1;

    // ---- prologue: input tile DMA (clamped) + weight planes 0..2
    for (int it = 0; it < 7; ++it) {
        int c = it * 256 + tid;
        if (c < 1728) {                       // 1728 % 64 == 0: whole waves
            int row  = c / 288;
            int rem  = c - row * 288;
            int px_i = rem >> 4;
            int bo   = (rem & 15) * 16;
            int cy = min(max(ty0 + row, 0), H - 1);
            int cx = min(max(tx0 + px_i, 0), W - 1);
            char* ldsb = IT + (it * 256 + (tid & ~63)) * 16;
            gload16(actin + cy * ROWB + cx * 256 + bo, ldsb);
        }
    }
#pragma unroll
    for (int pl = 0; pl < 3; ++pl) {
        const char* src = wpl + pl * 8192;
        char* dst = WQ + pl * 8192;
        gload16(src + (0 * 256 + tid) * 16, dst + (0 * 256 + (tid & ~63)) * 16);
        gload16(src + (1 * 256 + tid) * 16, dst + (1 * 256 + (tid & ~63)) * 16);
    }
    asm volatile("s_waitcnt vmcnt(6)" ::: "memory");   // input landed
    for (int c = tid; c < 1728; c += 256) {            // zero OOB borders
        int row  = c / 288;
        int rem  = c - row * 288;
        int px_i = rem >> 4;
        int gy = ty0 + row, gx = tx0 + px_i;
        if ((unsigned)gy >= (unsigned)H || (unsigned)gx >= (unsigned)W) {
            f32x4 z = {0.f, 0.f, 0.f, 0.f};
            *(f32x4*)(IT + c * 16) = z;
        }
    }
    LGKM0();
    BARRIER();

    f32x4 acc[4][2];
#pragma unroll
    for (int cf = 0; cf < 4; ++cf)
#pragma unroll
        for (int pf = 0; pf < 2; ++pf)
            acc[cf][pf] = (f32x4){0.f, 0.f, 0.f, 0.f};

#define CSTAGE(J, WN) {                                                        \
    if ((J) <= 32) {                                                           \
        const char* src = wpl + ((J) + 3) * 8192;                              \
        char* dst = WQ + (((J) + 3) & 3) * 8192;                               \
        gload16(src + (0*256 + tid) * 16, dst + (0*256 + (tid & ~63)) * 16);   \
        gload16(src + (1*256 + tid) * 16, dst + (1*256 + (tid & ~63)) * 16);   \
    }                                                                          \
    asm volatile("s_waitcnt vmcnt(" #WN ")" ::: "memory");                     \
    {                                                                          \
        const int tap = (J) >> 2, kk = (J) & 3;                                \
        const int r = tap / 3, s = tap - r * 3;                                \
        const int kb = kk * 64 + g * 16;                                       \
        const int keyb = ((i15 + s + 7) & 7) << 5;                             \
        const char* wbase = WQ + ((J) & 3) * 8192 + (wc * 64 + i15) * 64 + g * 16; \
        bf16x8 a0 = *(const bf16x8*)(wbase + 0 * 1024);                        \
        bf16x8 a1 = *(const bf16x8*)(wbase + 1 * 1024);                        \
        bf16x8 a2 = *(const bf16x8*)(wbase + 2 * 1024);                        \
        bf16x8 a3 = *(const bf16x8*)(wbase + 3 * 1024);                        \
        const char* ib = IT + (i15 + s) * 256 + (kb ^ keyb);                   \
        bf16x8 b0 = *(const bf16x8*)(ib + (wp * 2 + 0 + r) * 4608);            \
        bf16x8 b1 = *(const bf16x8*)(ib + (wp * 2 + 1 + r) * 4608);            \
        acc[0][0] = __builtin_amdgcn_mfma_f32_16x16x32_bf16(a0, b0, acc[0][0], 0, 0, 0); \
        acc[0][1] = __builtin_amdgcn_mfma_f32_16x16x32_bf16(a0, b1, acc[0][1], 0, 0, 0); \
        acc[1][0] = __builtin_amdgcn_mfma_f32_16x16x32_bf16(a1, b0, acc[1][0], 0, 0, 0); \
        acc[1][1] = __builtin_amdgcn_mfma_f32_16x16x32_bf16(a1, b1, acc[1][1], 0, 0, 0); \
        acc[2][0] = __builtin_amdgcn_mfma_f32_16x16x32_bf16(a2, b0, acc[2][0], 0, 0, 0); \
        acc[2][1] = __builtin_amdgcn_mfma_f32_16x16x32_bf16(a2, b1, acc[2][1], 0, 0, 0); \
        acc[3][0] = __builtin_amdgcn_mfma_f32_16x16x32_bf16(a3, b0, acc[3][0], 0, 0, 0); \
        acc[3][1] = __builtin_amdgcn_mfma_f32_16x16x32_bf16(a3, b1, acc[3][1], 0, 0, 0); \
    }                                                                          \
    BARRIER();                                                                 \
}

    CSTAGE(0,4)  CSTAGE(1,4)  CSTAGE(2,4)  CSTAGE(3,4)  CSTAGE(4,4)  CSTAGE(5,4)
    CSTAGE(6,4)  CSTAGE(7,4)  CSTAGE(8,4)  CSTAGE(9,4)  CSTAGE(10,4) CSTAGE(11,4)
    CSTAGE(12,4) CSTAGE(13,4) CSTAGE(14,4) CSTAGE(15,4) CSTAGE(16,4) CSTAGE(17,4)
    CSTAGE(18,4) CSTAGE(19,4) CSTAGE(20,4) CSTAGE(21,4) CSTAGE(22,4) CSTAGE(23,4)
    CSTAGE(24,4) CSTAGE(25,4) CSTAGE(26,4) CSTAGE(27,4) CSTAGE(28,4) CSTAGE(29,4)
    CSTAGE(30,4) CSTAGE(31,4) CSTAGE(32,4) CSTAGE(33,2) CSTAGE(34,0) CSTAGE(35,0)
#undef CSTAGE

    if (PROJ == 0) {
        // ---- epilogue: BN + ReLU + bf16 swizzled NHWC store
        const int gx = bx * 16 + i15;
        const int keyo = (gx & 7) << 5;
#pragma unroll
        for (int cf = 0; cf < 4; ++cf) {
            int co0 = wc * 64 + cf * 16 + g * 4;
            f32x4 inv4 = *(const f32x4*)&invshift_l[co0];
            f32x4 sh4  = *(const f32x4*)&invshift_l[128 + co0];
#pragma unroll
            for (int pf = 0; pf < 2; ++pf) {
                int gy = by * 4 + wp * 2 + pf;
                f32x4 v = acc[cf][pf];
                ushort4v o;
                o.x = f2b(fmaxf(v.x * inv4.x + sh4.x, 0.f));
                o.y = f2b(fmaxf(v.y * inv4.y + sh4.y, 0.f));
                o.z = f2b(fmaxf(v.z * inv4.z + sh4.z, 0.f));
                o.w = f2b(fmaxf(v.w * inv4.w + sh4.w, 0.f));
                *(ushort4v*)(actout + gy * ROWB + gx * 256 + ((co0 * 2) ^ keyo)) = o;
            }
        }
    } else {
        // ---- fused projection epilogue (layer 4 output never leaves LDS)
        float* actF = (float*)(smem + 27648);   // 64 px x 128 ch f32 (32 KB)
        float* spw  = (float*)smem;             // 1024 f32 inside dead IT
#pragma unroll
        for (int cf = 0; cf < 4; ++cf) {
            int co0 = wc * 64 + cf * 16 + g * 4;
            f32x4 inv4 = *(const f32x4*)&invshift_l[co0];
            f32x4 sh4  = *(const f32x4*)&invshift_l[128 + co0];
#pragma unroll
            for (int pf = 0; pf < 2; ++pf) {
                int pxi = (wp * 2 + pf) * 16 + i15;
                f32x4 v = acc[cf][pf];
                f32x4 o;
                o.x = fmaxf(v.x * inv4.x + sh4.x, 0.f);
                o.y = fmaxf(v.y * inv4.y + sh4.y, 0.f);
                o.z = fmaxf(v.z * inv4.z + sh4.z, 0.f);
                o.w = fmaxf(v.w * inv4.w + sh4.w, 0.f);
                *(f32x4*)&actF[pxi * 128 + (co0 ^ ((pxi & 7) << 2))] = o;
            }
        }
        for (int i = tid; i < 1024; i += 256) spw[i] = pw[i];
        LGKM0();
        BARRIER();
        int pxt = tid >> 2;           // 0..63
        int o0  = (tid & 3) * 2;      // 0,2,4,6
        float s0 = 0.f, s1 = 0.f;
#pragma unroll
        for (int ci = 0; ci < 128; ci += 4) {
            f32x4 a  = *(const f32x4*)&actF[pxt * 128 + (ci ^ ((pxt & 7) << 2))];
            f32x4 w0 = *(const f32x4*)&spw[o0 * 128 + ci];
            f32x4 w1 = *(const f32x4*)&spw[(o0 + 1) * 128 + ci];
            s0 += a.x * w0.x + a.y * w0.y + a.z * w0.z + a.w * w0.w;
            s1 += a.x * w1.x + a.y * w1.y + a.z * w1.z + a.w * w1.w;
        }
        int p = (by * 4 + (pxt >> 4)) * W + bx * 16 + (pxt & 15);
        mf[o0 * HW + p]       = s0 + pb[o0];
        mf[(o0 + 1) * HW + p] = s1 + pb[o0 + 1];
    }
}

// ===========================================================================
// ctrl: controller conv at the K=100 detection points (fp32)
// ===========================================================================
__global__ __launch_bounds__(256) void ctrl_kernel(
    const float* __restrict__ feat, const float* __restrict__ cw,
    const float* __restrict__ cb, const int* __restrict__ det,
    float* __restrict__ params)
{
    __shared__ float patch[1152];
    const int tid = threadIdx.x;
    const int k = blockIdx.x;
    const int xk = det[2 * k];
    const int yk = det[2 * k + 1];

    for (int i = tid; i < 1152; i += 256) {
        int ci = i / 9;
        int rem = i - ci * 9;
        int r = rem / 3, s = rem - r * 3;
        int gy = yk + r - 1, gx = xk + s - 1;
        float v = 0.f;
        if ((unsigned)gy < (unsigned)H && (unsigned)gx < (unsigned)W)
            v = feat[ci * HW + gy * W + gx];
        patch[i] = v;
    }
    __syncthreads();

    if (tid < 169) {
        float acc = cb[tid];
        const float4* cw4 = (const float4*)&cw[tid * 1152];
        const float4* p4  = (const float4*)patch;
        for (int i = 0; i < 288; ++i) {
            float4 a = p4[i];
            float4 b = cw4[i];
            acc += a.x * b.x + a.y * b.y + a.z * b.z + a.w * b.w;
        }
        params[k * 169 + tid] = acc;
    }
}

// ===========================================================================
// head: 10 detections per block; mf read once, reused 10x.
// Grid (100 px-tiles, 10 k-groups) x 256.
// ===========================================================================
__global__ __launch_bounds__(256) void head_kernel(
    const float* __restrict__ mf, const float* __restrict__ params,
    const int* __restrict__ det, float* __restrict__ out)
{
    __shared__ float sp[1690];
    __shared__ int sdet[20];
    const int tid = threadIdx.x;
    const int kg = blockIdx.y;
    for (int i = tid; i < 1690; i += 256) sp[i] = params[kg * 1690 + i];
    if (tid < 20) sdet[tid] = det[kg * 20 + tid];
    __syncthreads();

    const int p = blockIdx.x * 256 + tid;
    const int x = p % W;
    const int y = p / W;
    const float fx = (float)(x * 4 + 2);
    const float fy = (float)(y * 4 + 2);

    float f[8];
#pragma unroll
    for (int o = 0; o < 8; ++o) f[o] = mf[o * HW + p];

#pragma unroll 2
    for (int j = 0; j < 10; ++j) {
        const float* spj = &sp[j * 169];
        const float rel0 = (float)(sdet[2 * j] * 4) - fx;
        const float rel1 = (float)(sdet[2 * j + 1] * 4) - fy;
        float h0[8];
#pragma unroll
        for (int o = 0; o < 8; ++o) {
            float a = spj[152 + o] + spj[o * 10] * rel0 + spj[o * 10 + 1] * rel1;
#pragma unroll
            for (int c = 0; c < 8; ++c) a += spj[o * 10 + 2 + c] * f[c];
            h0[o] = fmaxf(a, 0.f);
        }
        float h1[8];
#pragma unroll
        for (int o = 0; o < 8; ++o) {
            float a = spj[160 + o];
#pragma unroll
            for (int c = 0; c < 8; ++c) a += spj[80 + o * 8 + c] * h0[c];
            h1[o] = fmaxf(a, 0.f);
        }
        float r = spj[168];
#pragma unroll
        for (int c = 0; c < 8; ++c) r += spj[144 + c] * h1[c];
        out[(kg * 10 + j) * HW + p] = r;
    }
}

// ===========================================================================
extern "C" void kernel_launch(void* const* d_in, const int* in_sizes, int n_in,
                              void* d_out, int out_size, void* d_ws, size_t ws_size,
                              hipStream_t stream)
{
    const float* cnn    = (const float*)d_in[0];
    const float* towerw = (const float*)d_in[1];
    const float* gamma  = (const float*)d_in[2];
    const float* beta   = (const float*)d_in[3];
    const float* meanp  = (const float*)d_in[4];
    const float* varp   = (const float*)d_in[5];
    const float* projw  = (const float*)d_in[6];
    const float* projb  = (const float*)d_in[7];
    const float* ctrlw  = (const float*)d_in[8];
    const float* ctrlb  = (const float*)d_in[9];
    const int*   det    = (const int*)d_in[10];
    float* out = (float*)d_out;

    char*  outb     = (char*)d_out;
    char*  X        = outb;                          // 6,553,600 B
    char*  wbf      = outb + 6553600;                // 1,179,648 B
    float* invshift = (float*)(outb + 7733248);      // 4,096 B

    char*  Y      = (char*)d_ws;                     // 6,553,600 B
    float* mf     = (float*)((char*)d_ws + 6553600); // 819,200 B
    float* params = (float*)((char*)d_ws + 7372800); // 67,600 B

    const dim3 blk(256);

    prep_weights<<<dim3(2304), blk, 0, stream>>>(towerw, gamma, beta, meanp, varp,
                                                 wbf, invshift);
    prep_input<<<dim3(1600), blk, 0, stream>>>(cnn, X);

    const dim3 cgrid(10, 40);
    conv_mfma<0><<<cgrid, blk, 0, stream>>>(X, wbf + 0 * 294912, invshift + 0 * 256,
                                            Y, nullptr, nullptr, nullptr);
    conv_mfma<0><<<cgrid, blk, 0, stream>>>(Y, wbf + 1 * 294912, invshift + 1 * 256,
                                            X, nullptr, nullptr, nullptr);
    conv_mfma<0><<<cgrid, blk, 0, stream>>>(X, wbf + 2 * 294912, invshift + 2 * 256,
                                            Y, nullptr, nullptr, nullptr);
    conv_mfma<1><<<cgrid, blk, 0, stream>>>(Y, wbf + 3 * 294912, invshift + 3 * 256,
                                            nullptr, projw, projb, mf);

    ctrl_kernel<<<dim3(100), blk, 0, stream>>>(cnn, ctrlw, ctrlb, det, params);
    head_kernel<<<dim3(100, 10), blk, 0, stream>>>(mf, params, det, out);
}